// Round 7
// baseline (5836.344 us; speedup 1.0000x reference)
//
#include <hip/hip_runtime.h>
#include <hip/hip_bf16.h>

#define BB 32
#define NN 520
#define MM 520
#define EE 128
#define HH 8
#define DKK 16
#define FFH_ 512
#define NL_ 6
#define DEPOT_ 20
#define LL 40

// ---------------- embedding: depot/customer linear ----------------
__global__ __launch_bounds__(256) void embed_k(
    const float* __restrict__ dep, const float* __restrict__ cus,
    const float* __restrict__ Wd, const float* __restrict__ bd,
    const float* __restrict__ Wc3, const float* __restrict__ bc,
    float* __restrict__ x)
{
    int idx = blockIdx.x * 256 + threadIdx.x;   // < B*N*E = 2129920
    int e = idx & 127;
    int bn = idx >> 7;
    int n = bn % NN;
    int b = bn / NN;
    float a;
    if (n < DEPOT_) {
        a = bd[e];
        const float* f = dep + ((size_t)(b * DEPOT_ + n)) * 4;
        #pragma unroll
        for (int j = 0; j < 4; j++) a += f[j] * Wd[e * 4 + j];
    } else {
        a = bc[e];
        const float* f = cus + ((size_t)(b * 500 + (n - DEPOT_))) * 3;
        #pragma unroll
        for (int j = 0; j < 3; j++) a += f[j] * Wc3[e * 3 + j];
    }
    x[idx] = a;
}

// ---------------- 64x64-tile GEMM: C[m,n] = sum_k A[m,k]*W[n,k] + bias[n] ----------------
#define GT 64
#define GK 32
#define GP 36
__global__ __launch_bounds__(256) void gemm64_k(
    const float* __restrict__ A, int lda,
    const float* __restrict__ W, int ldw,
    const float* __restrict__ bias,
    float* __restrict__ C, int ldc,
    int K, int relu)
{
    __shared__ float As[GT][GP];
    __shared__ float Ws[GT][GP];
    int t = threadIdx.x;
    int tx = t & 15, ty = t >> 4;
    int m0 = blockIdx.y * GT, n0 = blockIdx.x * GT;
    int lr = t >> 2, lc = (t & 3) * 8;
    float acc[4][4];
    #pragma unroll
    for (int i = 0; i < 4; i++)
        #pragma unroll
        for (int j = 0; j < 4; j++) acc[i][j] = 0.0f;

    for (int k0 = 0; k0 < K; k0 += GK) {
        const float* Ap = A + (size_t)(m0 + lr) * lda + k0 + lc;
        const float* Wp = W + (size_t)(n0 + lr) * ldw + k0 + lc;
        float4 av0 = *((const float4*)Ap), av1 = *((const float4*)(Ap + 4));
        float4 wv0 = *((const float4*)Wp), wv1 = *((const float4*)(Wp + 4));
        *((float4*)&As[lr][lc]) = av0; *((float4*)&As[lr][lc + 4]) = av1;
        *((float4*)&Ws[lr][lc]) = wv0; *((float4*)&Ws[lr][lc + 4]) = wv1;
        __syncthreads();
        #pragma unroll
        for (int kk = 0; kk < GK; kk += 2) {
            float2 a0 = *((const float2*)&As[ty][kk]);
            float2 a1 = *((const float2*)&As[ty + 16][kk]);
            float2 a2 = *((const float2*)&As[ty + 32][kk]);
            float2 a3 = *((const float2*)&As[ty + 48][kk]);
            float2 w0 = *((const float2*)&Ws[tx][kk]);
            float2 w1 = *((const float2*)&Ws[tx + 16][kk]);
            float2 w2 = *((const float2*)&Ws[tx + 32][kk]);
            float2 w3 = *((const float2*)&Ws[tx + 48][kk]);
            acc[0][0] += a0.x * w0.x + a0.y * w0.y;
            acc[0][1] += a0.x * w1.x + a0.y * w1.y;
            acc[0][2] += a0.x * w2.x + a0.y * w2.y;
            acc[0][3] += a0.x * w3.x + a0.y * w3.y;
            acc[1][0] += a1.x * w0.x + a1.y * w0.y;
            acc[1][1] += a1.x * w1.x + a1.y * w1.y;
            acc[1][2] += a1.x * w2.x + a1.y * w2.y;
            acc[1][3] += a1.x * w3.x + a1.y * w3.y;
            acc[2][0] += a2.x * w0.x + a2.y * w0.y;
            acc[2][1] += a2.x * w1.x + a2.y * w1.y;
            acc[2][2] += a2.x * w2.x + a2.y * w2.y;
            acc[2][3] += a2.x * w3.x + a2.y * w3.y;
            acc[3][0] += a3.x * w0.x + a3.y * w0.y;
            acc[3][1] += a3.x * w1.x + a3.y * w1.y;
            acc[3][2] += a3.x * w2.x + a3.y * w2.y;
            acc[3][3] += a3.x * w3.x + a3.y * w3.y;
        }
        __syncthreads();
    }
    #pragma unroll
    for (int j = 0; j < 4; j++) {
        float bv = bias ? bias[n0 + tx + 16 * j] : 0.0f;
        #pragma unroll
        for (int i = 0; i < 4; i++) {
            float v = acc[i][j] + bv;
            if (relu) v = fmaxf(v, 0.0f);
            C[(size_t)(m0 + ty + 16 * i) * ldc + n0 + tx + 16 * j] = v;
        }
    }
}

// ---------------- score GEMM (NT) with tanh epilogue ----------------
__global__ __launch_bounds__(256) void sgemm_k(
    const float* __restrict__ A,    // score [B*520][128]
    const float* __restrict__ Enc,  // [B*520][128]
    float* __restrict__ C)          // [B][520][520]
{
    __shared__ float As[GT][GP];
    __shared__ float Ws[GT][GP];
    int t = threadIdx.x;
    int tx = t & 15, ty = t >> 4;
    int b = blockIdx.z;
    int m0 = blockIdx.y * GT, n0 = blockIdx.x * GT;
    int lr = t >> 2, lc = (t & 3) * 8;
    int mr = m0 + lr; if (mr >= NN) mr = NN - 1;
    int nr = n0 + lr; if (nr >= NN) nr = NN - 1;
    float acc[4][4];
    #pragma unroll
    for (int i = 0; i < 4; i++)
        #pragma unroll
        for (int j = 0; j < 4; j++) acc[i][j] = 0.0f;

    for (int k0 = 0; k0 < EE; k0 += GK) {
        const float* Ap = A + ((size_t)(b * NN + mr)) * EE + k0 + lc;
        const float* Wp = Enc + ((size_t)(b * NN + nr)) * EE + k0 + lc;
        float4 av0 = *((const float4*)Ap), av1 = *((const float4*)(Ap + 4));
        float4 wv0 = *((const float4*)Wp), wv1 = *((const float4*)(Wp + 4));
        *((float4*)&As[lr][lc]) = av0; *((float4*)&As[lr][lc + 4]) = av1;
        *((float4*)&Ws[lr][lc]) = wv0; *((float4*)&Ws[lr][lc + 4]) = wv1;
        __syncthreads();
        #pragma unroll
        for (int kk = 0; kk < GK; kk += 2) {
            float2 a0 = *((const float2*)&As[ty][kk]);
            float2 a1 = *((const float2*)&As[ty + 16][kk]);
            float2 a2 = *((const float2*)&As[ty + 32][kk]);
            float2 a3 = *((const float2*)&As[ty + 48][kk]);
            float2 w0 = *((const float2*)&Ws[tx][kk]);
            float2 w1 = *((const float2*)&Ws[tx + 16][kk]);
            float2 w2 = *((const float2*)&Ws[tx + 32][kk]);
            float2 w3 = *((const float2*)&Ws[tx + 48][kk]);
            acc[0][0] += a0.x * w0.x + a0.y * w0.y;
            acc[0][1] += a0.x * w1.x + a0.y * w1.y;
            acc[0][2] += a0.x * w2.x + a0.y * w2.y;
            acc[0][3] += a0.x * w3.x + a0.y * w3.y;
            acc[1][0] += a1.x * w0.x + a1.y * w0.y;
            acc[1][1] += a1.x * w1.x + a1.y * w1.y;
            acc[1][2] += a1.x * w2.x + a1.y * w2.y;
            acc[1][3] += a1.x * w3.x + a1.y * w3.y;
            acc[2][0] += a2.x * w0.x + a2.y * w0.y;
            acc[2][1] += a2.x * w1.x + a2.y * w1.y;
            acc[2][2] += a2.x * w2.x + a2.y * w2.y;
            acc[2][3] += a2.x * w3.x + a2.y * w3.y;
            acc[3][0] += a3.x * w0.x + a3.y * w0.y;
            acc[3][1] += a3.x * w1.x + a3.y * w1.y;
            acc[3][2] += a3.x * w2.x + a3.y * w2.y;
            acc[3][3] += a3.x * w3.x + a3.y * w3.y;
        }
        __syncthreads();
    }
    #pragma unroll
    for (int i = 0; i < 4; i++) {
        int m = m0 + ty + 16 * i;
        if (m >= NN) continue;
        #pragma unroll
        for (int j = 0; j < 4; j++) {
            int n = n0 + tx + 16 * j;
            if (n >= NN) continue;
            float v = 10.0f * tanhf(acc[i][j] * 0.088388347648318447f);
            C[((size_t)(b * NN + m)) * NN + n] = v;
        }
    }
}

// ---------------- row softmax: out = softmax(logits + mask) ----------------
__global__ __launch_bounds__(64) void smax_k(
    const float* __restrict__ L, const float* __restrict__ mask,
    float* __restrict__ out)
{
    int bm = blockIdx.x;
    int t = threadIdx.x;
    const float* Lr = L + (size_t)bm * NN;
    const float* Mr = mask + (size_t)bm * NN;
    float v[9];
    float mx = -1e30f;
    #pragma unroll
    for (int i = 0; i < 9; i++) {
        int idx = t + i * 64;
        if (idx < NN) { v[i] = Lr[idx] + Mr[idx]; mx = fmaxf(mx, v[i]); }
        else v[i] = -1e30f;
    }
    #pragma unroll
    for (int o = 32; o > 0; o >>= 1) mx = fmaxf(mx, __shfl_xor(mx, o));
    float s = 0.0f;
    #pragma unroll
    for (int i = 0; i < 9; i++) {
        int idx = t + i * 64;
        float e = (idx < NN) ? expf(v[i] - mx) : 0.0f;
        v[i] = e; s += e;
    }
    #pragma unroll
    for (int o = 32; o > 0; o >>= 1) s += __shfl_xor(s, o);
    float inv = 1.0f / s;
    #pragma unroll
    for (int i = 0; i < 9; i++) {
        int idx = t + i * 64;
        if (idx < NN) out[(size_t)bm * NN + idx] = v[i] * inv;
    }
}

// ---------------- register-tiled flash MHA (2 Q-rows/thread for occupancy) ----------------
// 256 thr; tx=t&15 (4 k-cols each), ty=t>>4 (2 q-rows each -> TQ=32);
// dg=t&3 (V dim group), mg=(t>>2)&3 (PV m-subrange, stride 4 rows = conflict-free).
// VGPR target ~90 (qs 32 + o 8 + s 8) -> 5+ waves/SIMD; LDS 18.2 KB.
#define TQ 32
#define TK 64
__global__ __launch_bounds__(256, 5) void fmha_k(
    const float* __restrict__ Q, const float* __restrict__ K,
    const float* __restrict__ V, const float* __restrict__ mask,
    float* __restrict__ O, int Nq, int Nk)
{
    int qt = blockIdx.x, h = blockIdx.y, b = blockIdx.z;
    int t = threadIdx.x;
    int tx = t & 15, ty = t >> 4;
    int dg = t & 3, mg = (t >> 2) & 3;
    int r_st = t >> 2, c_st = (t & 3) * 4;

    __shared__ float Kt[16][68];   // [dim][col]
    __shared__ float Vs[64][20];   // [m][dim]
    __shared__ float Ps[TQ][68];   // [row][m]

    int qr[2];
    float qs[2][16];
    #pragma unroll
    for (int i = 0; i < 2; i++) {
        int q = qt * TQ + ty * 2 + i;
        qr[i] = q;
        int qc = q < Nq ? q : Nq - 1;
        const float4* qp = (const float4*)(Q + ((size_t)(b * Nq + qc)) * EE + h * 16);
        #pragma unroll
        for (int c = 0; c < 4; c++) {
            float4 v = qp[c];
            qs[i][c * 4 + 0] = v.x; qs[i][c * 4 + 1] = v.y;
            qs[i][c * 4 + 2] = v.z; qs[i][c * 4 + 3] = v.w;
        }
    }

    float o[2][4];
    #pragma unroll
    for (int i = 0; i < 2; i++)
        #pragma unroll
        for (int j = 0; j < 4; j++) o[i][j] = 0.0f;
    float m_i[2] = {-1e30f, -1e30f};
    float l_i[2] = {0.0f, 0.0f};

    int nkt = (Nk + TK - 1) / TK;
    for (int kt = 0; kt < nkt; kt++) {
        int k0 = kt * TK;
        {
            int kr = k0 + r_st; int krc = kr < Nk ? kr : Nk - 1;
            float4 kv = *((const float4*)(K + ((size_t)(b * Nk + krc)) * EE + h * 16 + c_st));
            float4 vv = *((const float4*)(V + ((size_t)(b * Nk + krc)) * EE + h * 16 + c_st));
            Kt[c_st + 0][r_st] = kv.x;
            Kt[c_st + 1][r_st] = kv.y;
            Kt[c_st + 2][r_st] = kv.z;
            Kt[c_st + 3][r_st] = kv.w;
            *((float4*)&Vs[r_st][c_st]) = vv;
        }
        __syncthreads();

        // QK: s[2 rows][4 cols], cols = tx*4+j
        float s[2][4];
        #pragma unroll
        for (int i = 0; i < 2; i++)
            #pragma unroll
            for (int j = 0; j < 4; j++) s[i][j] = 0.0f;
        #pragma unroll
        for (int k = 0; k < 16; k++) {
            float4 kv4 = *((const float4*)&Kt[k][tx * 4]);
            #pragma unroll
            for (int i = 0; i < 2; i++) {
                float qv = qs[i][k];
                s[i][0] += qv * kv4.x;
                s[i][1] += qv * kv4.y;
                s[i][2] += qv * kv4.z;
                s[i][3] += qv * kv4.w;
            }
        }

        // scale + mask + col bounds
        int c0 = k0 + tx * 4;
        #pragma unroll
        for (int i = 0; i < 2; i++) {
            float mv0 = 0, mv1 = 0, mv2 = 0, mv3 = 0;
            if (mask) {
                int qc = qr[i] < Nq ? qr[i] : Nq - 1;
                const float* mr = mask + ((size_t)(b * Nq + qc)) * Nk;
                if (c0 + 3 < Nk) {
                    float4 m4 = *((const float4*)(mr + c0));
                    mv0 = m4.x; mv1 = m4.y; mv2 = m4.z; mv3 = m4.w;
                } else {
                    if (c0 + 0 < Nk) mv0 = mr[c0 + 0];
                    if (c0 + 1 < Nk) mv1 = mr[c0 + 1];
                    if (c0 + 2 < Nk) mv2 = mr[c0 + 2];
                    if (c0 + 3 < Nk) mv3 = mr[c0 + 3];
                }
            }
            s[i][0] = (c0 + 0 < Nk) ? (s[i][0] * 0.25f + mv0) : -1e30f;
            s[i][1] = (c0 + 1 < Nk) ? (s[i][1] * 0.25f + mv1) : -1e30f;
            s[i][2] = (c0 + 2 < Nk) ? (s[i][2] * 0.25f + mv2) : -1e30f;
            s[i][3] = (c0 + 3 < Nk) ? (s[i][3] * 0.25f + mv3) : -1e30f;
        }

        // online softmax per row (stats shared across tx lanes = bits 0-3)
        #pragma unroll
        for (int i = 0; i < 2; i++) {
            float mloc = fmaxf(fmaxf(s[i][0], s[i][1]), fmaxf(s[i][2], s[i][3]));
            mloc = fmaxf(mloc, __shfl_xor(mloc, 1));
            mloc = fmaxf(mloc, __shfl_xor(mloc, 2));
            mloc = fmaxf(mloc, __shfl_xor(mloc, 4));
            mloc = fmaxf(mloc, __shfl_xor(mloc, 8));
            float m_new = fmaxf(m_i[i], mloc);
            float alpha = __expf(m_i[i] - m_new);
            float p0 = __expf(s[i][0] - m_new);
            float p1 = __expf(s[i][1] - m_new);
            float p2 = __expf(s[i][2] - m_new);
            float p3 = __expf(s[i][3] - m_new);
            s[i][0] = p0; s[i][1] = p1; s[i][2] = p2; s[i][3] = p3;
            float ls = p0 + p1 + p2 + p3;
            ls += __shfl_xor(ls, 1);
            ls += __shfl_xor(ls, 2);
            ls += __shfl_xor(ls, 4);
            ls += __shfl_xor(ls, 8);
            l_i[i] = l_i[i] * alpha + ls;
            m_i[i] = m_new;
            o[i][0] *= alpha; o[i][1] *= alpha; o[i][2] *= alpha; o[i][3] *= alpha;
        }

        // write P (rows ty*2+i; per-phase 2-way = free)
        #pragma unroll
        for (int i = 0; i < 2; i++) {
            float4 pw; pw.x = s[i][0]; pw.y = s[i][1]; pw.z = s[i][2]; pw.w = s[i][3];
            *((float4*)&Ps[ty * 2 + i][tx * 4]) = pw;
        }
        __syncthreads();

        // PV: partial over m quads mq*16 + mg*4, dims dg*4..+3
        #pragma unroll
        for (int mq = 0; mq < 4; mq++) {
            int m0 = mq * 16 + mg * 4;
            float4 pr0 = *((const float4*)&Ps[ty * 2 + 0][m0]);
            float4 pr1 = *((const float4*)&Ps[ty * 2 + 1][m0]);
            float4 v0 = *((const float4*)&Vs[m0 + 0][dg * 4]);
            float4 v1 = *((const float4*)&Vs[m0 + 1][dg * 4]);
            float4 v2 = *((const float4*)&Vs[m0 + 2][dg * 4]);
            float4 v3 = *((const float4*)&Vs[m0 + 3][dg * 4]);
            o[0][0] += pr0.x * v0.x + pr0.y * v1.x + pr0.z * v2.x + pr0.w * v3.x;
            o[0][1] += pr0.x * v0.y + pr0.y * v1.y + pr0.z * v2.y + pr0.w * v3.y;
            o[0][2] += pr0.x * v0.z + pr0.y * v1.z + pr0.z * v2.z + pr0.w * v3.z;
            o[0][3] += pr0.x * v0.w + pr0.y * v1.w + pr0.z * v2.w + pr0.w * v3.w;
            o[1][0] += pr1.x * v0.x + pr1.y * v1.x + pr1.z * v2.x + pr1.w * v3.x;
            o[1][1] += pr1.x * v0.y + pr1.y * v1.y + pr1.z * v2.y + pr1.w * v3.y;
            o[1][2] += pr1.x * v0.z + pr1.y * v1.z + pr1.z * v2.z + pr1.w * v3.z;
            o[1][3] += pr1.x * v0.w + pr1.y * v1.w + pr1.z * v2.w + pr1.w * v3.w;
        }
        __syncthreads();
    }

    // reduce partial O over mg (lane bits 2,3)
    #pragma unroll
    for (int i = 0; i < 2; i++)
        #pragma unroll
        for (int j = 0; j < 4; j++) {
            o[i][j] += __shfl_xor(o[i][j], 4);
            o[i][j] += __shfl_xor(o[i][j], 8);
        }
    if (mg == 0) {
        #pragma unroll
        for (int i = 0; i < 2; i++) {
            if (qr[i] < Nq) {
                float inv = 1.0f / l_i[i];
                float4 ov;
                ov.x = o[i][0] * inv; ov.y = o[i][1] * inv;
                ov.z = o[i][2] * inv; ov.w = o[i][3] * inv;
                *((float4*)(O + ((size_t)(b * Nq + qr[i])) * EE + h * 16 + dg * 4)) = ov;
            }
        }
    }
}

// ---------------- InstanceNorm over node axis ----------------
__global__ __launch_bounds__(64) void inorm_k(
    const float* __restrict__ X, const float* __restrict__ Y,
    const float* __restrict__ g, const float* __restrict__ bb,
    float* __restrict__ Out)
{
    int be = blockIdx.x;
    int b = be >> 7, e = be & 127;
    int t = threadIdx.x;
    float vals[9];
    float s = 0.0f, s2 = 0.0f;
    int c = 0;
    for (int n = t; n < NN; n += 64) {
        size_t off = ((size_t)(b * NN + n)) * EE + e;
        float v = X[off] + Y[off];
        vals[c++] = v; s += v; s2 += v * v;
    }
    #pragma unroll
    for (int o = 32; o > 0; o >>= 1) { s += __shfl_down(s, o); s2 += __shfl_down(s2, o); }
    s = __shfl(s, 0); s2 = __shfl(s2, 0);
    float mu = s * (1.0f / NN);
    float var = s2 * (1.0f / NN) - mu * mu;
    float inv = rsqrtf(var + 1e-5f);
    float gg = g[e], bv = bb[e];
    c = 0;
    for (int n = t; n < NN; n += 64) {
        size_t off = ((size_t)(b * NN + n)) * EE + e;
        Out[off] = (vals[c++] - mu) * inv * gg + bv;
    }
}

__global__ void zero_k(float* p, int n) {
    int i = blockIdx.x * 256 + threadIdx.x;
    if (i < n) p[i] = 0.0f;
}

__global__ __launch_bounds__(128) void encsum_k(const float* __restrict__ enc, float* __restrict__ esum) {
    int b = blockIdx.x, ch = blockIdx.y, t = threadIdx.x;
    float a = 0.0f;
    for (int i = 0; i < 65; i++) {
        int n = ch * 65 + i;
        a += enc[((size_t)(b * NN + n)) * EE + t];
    }
    atomicAdd(&esum[b * EE + t], a);
}

// mt[b,e] = sum_f (esum[b,f]/N) * Wr[e, 128+f]
__global__ __launch_bounds__(128) void meanterm_k(
    const float* __restrict__ esum, const float* __restrict__ Wr, float* __restrict__ mt)
{
    int b = blockIdx.x, t = threadIdx.x;
    __shared__ float em[128];
    em[t] = esum[b * EE + t] * (1.0f / NN);
    __syncthreads();
    const float* w = Wr + (size_t)t * 257 + 128;
    float a = 0.0f;
    for (int f = 0; f < 128; f++) a += em[f] * w[f];
    mt[b * EE + t] = a;
}

__global__ __launch_bounds__(128) void subtour_k(
    const float* __restrict__ enc, const int* __restrict__ subn,
    const int* __restrict__ subl, float* __restrict__ subm)
{
    int bm = blockIdx.x;
    int b = bm / MM;
    int t = threadIdx.x;
    int len = subl[bm];
    float acc = 0.0f; int cnt = 0;
    for (int l = 0; l < LL; l++) {
        int node = subn[(size_t)bm * LL + l];
        if (l < len && node >= DEPOT_) {
            acc += enc[((size_t)(b * NN + node)) * EE + t];
            cnt++;
        }
    }
    float cf = (float)(cnt < 1 ? 1 : cnt);
    subm[(size_t)bm * EE + t] = acc / cf;
}

__global__ __launch_bounds__(128) void decq_k(
    const float* __restrict__ enc, const float* __restrict__ subm,
    const float* __restrict__ mterm, const int* __restrict__ cur,
    const float* __restrict__ loadv, const int* __restrict__ sel,
    const float* __restrict__ Wl, const float* __restrict__ Wr,
    float* __restrict__ out)
{
    int bm = blockIdx.x;
    int b = bm / MM;
    int t = threadIdx.x;
    __shared__ float le[128], sm[128];
    int cn = cur[bm];
    le[t] = enc[((size_t)(b * NN + cn)) * EE + t];
    sm[t] = subm[(size_t)bm * EE + t];
    __syncthreads();
    int s2v = sel[(size_t)bm * 4 + 2];   // selected[:,:,-2]
    bool flag = (s2v >= DEPOT_) && (cn < DEPOT_);
    float q;
    if (flag) {
        const float* w = Wl + (size_t)t * 256;
        float a = 0.0f;
        for (int f = 0; f < 128; f++) a += le[f] * w[f];
        for (int f = 0; f < 128; f++) a += sm[f] * w[128 + f];
        q = a;
    } else {
        const float* w = Wr + (size_t)t * 257;
        float a = mterm[b * EE + t] + loadv[bm] * w[256];
        for (int f = 0; f < 128; f++) a += le[f] * w[f];
        q = a;
    }
    out[(size_t)bm * EE + t] = q;
}

extern "C" void kernel_launch(void* const* d_in, const int* in_sizes, int n_in,
                              void* d_out, int out_size, void* d_ws, size_t ws_size,
                              hipStream_t stream)
{
    const float* depot = (const float*)d_in[0];
    const float* cust  = (const float*)d_in[1];
    const float* mask  = (const float*)d_in[2];
    const float* loadv = (const float*)d_in[3];
    const int*  cur   = (const int*)d_in[4];
    const int*  subn  = (const int*)d_in[5];
    const int*  subl  = (const int*)d_in[6];
    const int*  sel   = (const int*)d_in[7];
    const float* Wdep  = (const float*)d_in[8];
    const float* bdep  = (const float*)d_in[9];
    const float* Wcus  = (const float*)d_in[10];
    const float* bcus  = (const float*)d_in[11];
    const float* Wq    = (const float*)d_in[12];
    const float* Wk    = (const float*)d_in[13];
    const float* Wv    = (const float*)d_in[14];
    const float* Wc    = (const float*)d_in[15];
    const float* Wcb   = (const float*)d_in[16];
    const float* n1g   = (const float*)d_in[17];
    const float* n1b   = (const float*)d_in[18];
    const float* fW1   = (const float*)d_in[19];
    const float* fb1   = (const float*)d_in[20];
    const float* fW2   = (const float*)d_in[21];
    const float* fb2   = (const float*)d_in[22];
    const float* n2g   = (const float*)d_in[23];
    const float* n2b   = (const float*)d_in[24];
    const float* Wql   = (const float*)d_in[25];
    const float* Wqr   = (const float*)d_in[26];
    const float* dWk   = (const float*)d_in[27];
    const float* dWv   = (const float*)d_in[28];
    const float* dWc   = (const float*)d_in[29];
    const float* dWcb  = (const float*)d_in[30];

    const size_t SZ = (size_t)BB * NN * EE;           // 2,129,920
    float* f0 = (float*)d_ws;       // x / encoded
    float* f1 = f0 + SZ;            // q / k_d / logits (spans f1..f5)
    float* f2 = f1 + SZ;            // k / v_d
    float* f3 = f2 + SZ;            // v / encsum + meanterm
    float* f4 = f3 + SZ;            // mh,ff2 out / sub_mean, dec attn
    float* f5 = f4 + SZ;            // x1 / final_q
    float* big = f5 + SZ;           // ffh (B*N*FFH) / dec score

    dim3 g4(EE / GT, (BB * NN) / GT);     // (2, 260)
    dim3 g16(FFH_ / GT, (BB * NN) / GT);  // (8, 260)
    dim3 gmha((NN + TQ - 1) / TQ, HH, BB);  // (17, 8, 32)
    dim3 gsc((NN + GT - 1) / GT, (NN + GT - 1) / GT, BB);  // (9, 9, 32)

    embed_k<<<(BB * NN * EE) / 256, 256, 0, stream>>>(depot, cust, Wdep, bdep, Wcus, bcus, f0);

    for (int i = 0; i < NL_; i++) {
        const float* wq = Wq + (size_t)i * EE * EE;
        const float* wk = Wk + (size_t)i * EE * EE;
        const float* wv = Wv + (size_t)i * EE * EE;
        const float* wc = Wc + (size_t)i * EE * EE;
        gemm64_k<<<g4, 256, 0, stream>>>(f0, EE, wq, EE, nullptr, f1, EE, EE, 0);
        gemm64_k<<<g4, 256, 0, stream>>>(f0, EE, wk, EE, nullptr, f2, EE, EE, 0);
        gemm64_k<<<g4, 256, 0, stream>>>(f0, EE, wv, EE, nullptr, f3, EE, EE, 0);
        fmha_k<<<gmha, 256, 0, stream>>>(f1, f2, f3, nullptr, f4, NN, NN);
        gemm64_k<<<g4, 256, 0, stream>>>(f4, EE, wc, EE, Wcb + i * EE, f1, EE, EE, 0);
        inorm_k<<<BB * EE, 64, 0, stream>>>(f0, f1, n1g + i * EE, n1b + i * EE, f5);
        gemm64_k<<<g16, 256, 0, stream>>>(f5, EE, fW1 + (size_t)i * FFH_ * EE, EE, fb1 + i * FFH_, big, FFH_, EE, 1);
        gemm64_k<<<g4, 256, 0, stream>>>(big, FFH_, fW2 + (size_t)i * EE * FFH_, FFH_, fb2 + i * EE, f1, EE, FFH_, 0);
        inorm_k<<<BB * EE, 64, 0, stream>>>(f5, f1, n2g + i * EE, n2b + i * EE, f0);
    }

    // ---- decoder ----
    gemm64_k<<<g4, 256, 0, stream>>>(f0, EE, dWk, EE, nullptr, f1, EE, EE, 0);
    gemm64_k<<<g4, 256, 0, stream>>>(f0, EE, dWv, EE, nullptr, f2, EE, EE, 0);

    zero_k<<<(BB * EE + 255) / 256, 256, 0, stream>>>(f3, BB * EE);
    encsum_k<<<dim3(BB, 8), 128, 0, stream>>>(f0, f3);
    meanterm_k<<<BB, 128, 0, stream>>>(f3, Wqr, f3 + BB * EE);

    subtour_k<<<BB * MM, 128, 0, stream>>>(f0, subn, subl, f4);
    decq_k<<<BB * MM, 128, 0, stream>>>(f0, f4, f3 + BB * EE, cur, loadv, sel, Wql, Wqr, f5);

    fmha_k<<<gmha, 256, 0, stream>>>(f5, f1, f2, mask, f4, MM, NN);
    // dec score -> big (keeps f1..f5 free for the logits matrix)
    gemm64_k<<<g4, 256, 0, stream>>>(f4, EE, dWc, EE, dWcb, big, EE, EE, 0);

    // logits (B x 520 x 520) at f1 (spans f1..f5; all dead now)
    sgemm_k<<<gsc, 256, 0, stream>>>(big, f0, f1);
    smax_k<<<BB * MM, 64, 0, stream>>>(f1, mask, (float*)d_out);
}

// Round 8
// 3340.381 us; speedup vs baseline: 1.7472x; 1.7472x over previous
//
#include <hip/hip_runtime.h>
#include <hip/hip_bf16.h>

#define BB 32
#define NN 520
#define MM 520
#define EE 128
#define HH 8
#define DKK 16
#define FFH_ 512
#define NL_ 6
#define DEPOT_ 20
#define LL 40

// ---------------- embedding: depot/customer linear ----------------
__global__ __launch_bounds__(256) void embed_k(
    const float* __restrict__ dep, const float* __restrict__ cus,
    const float* __restrict__ Wd, const float* __restrict__ bd,
    const float* __restrict__ Wc3, const float* __restrict__ bc,
    float* __restrict__ x)
{
    int idx = blockIdx.x * 256 + threadIdx.x;   // < B*N*E = 2129920
    int e = idx & 127;
    int bn = idx >> 7;
    int n = bn % NN;
    int b = bn / NN;
    float a;
    if (n < DEPOT_) {
        a = bd[e];
        const float* f = dep + ((size_t)(b * DEPOT_ + n)) * 4;
        #pragma unroll
        for (int j = 0; j < 4; j++) a += f[j] * Wd[e * 4 + j];
    } else {
        a = bc[e];
        const float* f = cus + ((size_t)(b * 500 + (n - DEPOT_))) * 3;
        #pragma unroll
        for (int j = 0; j < 3; j++) a += f[j] * Wc3[e * 3 + j];
    }
    x[idx] = a;
}

// ---------------- 64x64-tile GEMM: C[m,n] = sum_k A[m,k]*W[n,k] + bias[n] ----------------
#define GT 64
#define GK 32
#define GP 36
__global__ __launch_bounds__(256) void gemm64_k(
    const float* __restrict__ A, int lda,
    const float* __restrict__ W, int ldw,
    const float* __restrict__ bias,
    float* __restrict__ C, int ldc,
    int K, int relu)
{
    __shared__ float As[GT][GP];
    __shared__ float Ws[GT][GP];
    int t = threadIdx.x;
    int tx = t & 15, ty = t >> 4;
    int m0 = blockIdx.y * GT, n0 = blockIdx.x * GT;
    int lr = t >> 2, lc = (t & 3) * 8;
    float acc[4][4];
    #pragma unroll
    for (int i = 0; i < 4; i++)
        #pragma unroll
        for (int j = 0; j < 4; j++) acc[i][j] = 0.0f;

    for (int k0 = 0; k0 < K; k0 += GK) {
        const float* Ap = A + (size_t)(m0 + lr) * lda + k0 + lc;
        const float* Wp = W + (size_t)(n0 + lr) * ldw + k0 + lc;
        float4 av0 = *((const float4*)Ap), av1 = *((const float4*)(Ap + 4));
        float4 wv0 = *((const float4*)Wp), wv1 = *((const float4*)(Wp + 4));
        *((float4*)&As[lr][lc]) = av0; *((float4*)&As[lr][lc + 4]) = av1;
        *((float4*)&Ws[lr][lc]) = wv0; *((float4*)&Ws[lr][lc + 4]) = wv1;
        __syncthreads();
        #pragma unroll
        for (int kk = 0; kk < GK; kk += 2) {
            float2 a0 = *((const float2*)&As[ty][kk]);
            float2 a1 = *((const float2*)&As[ty + 16][kk]);
            float2 a2 = *((const float2*)&As[ty + 32][kk]);
            float2 a3 = *((const float2*)&As[ty + 48][kk]);
            float2 w0 = *((const float2*)&Ws[tx][kk]);
            float2 w1 = *((const float2*)&Ws[tx + 16][kk]);
            float2 w2 = *((const float2*)&Ws[tx + 32][kk]);
            float2 w3 = *((const float2*)&Ws[tx + 48][kk]);
            acc[0][0] += a0.x * w0.x + a0.y * w0.y;
            acc[0][1] += a0.x * w1.x + a0.y * w1.y;
            acc[0][2] += a0.x * w2.x + a0.y * w2.y;
            acc[0][3] += a0.x * w3.x + a0.y * w3.y;
            acc[1][0] += a1.x * w0.x + a1.y * w0.y;
            acc[1][1] += a1.x * w1.x + a1.y * w1.y;
            acc[1][2] += a1.x * w2.x + a1.y * w2.y;
            acc[1][3] += a1.x * w3.x + a1.y * w3.y;
            acc[2][0] += a2.x * w0.x + a2.y * w0.y;
            acc[2][1] += a2.x * w1.x + a2.y * w1.y;
            acc[2][2] += a2.x * w2.x + a2.y * w2.y;
            acc[2][3] += a2.x * w3.x + a2.y * w3.y;
            acc[3][0] += a3.x * w0.x + a3.y * w0.y;
            acc[3][1] += a3.x * w1.x + a3.y * w1.y;
            acc[3][2] += a3.x * w2.x + a3.y * w2.y;
            acc[3][3] += a3.x * w3.x + a3.y * w3.y;
        }
        __syncthreads();
    }
    #pragma unroll
    for (int j = 0; j < 4; j++) {
        float bv = bias ? bias[n0 + tx + 16 * j] : 0.0f;
        #pragma unroll
        for (int i = 0; i < 4; i++) {
            float v = acc[i][j] + bv;
            if (relu) v = fmaxf(v, 0.0f);
            C[(size_t)(m0 + ty + 16 * i) * ldc + n0 + tx + 16 * j] = v;
        }
    }
}

// ---------------- score GEMM (NT) with tanh epilogue ----------------
__global__ __launch_bounds__(256) void sgemm_k(
    const float* __restrict__ A,    // score [B*520][128]
    const float* __restrict__ Enc,  // [B*520][128]
    float* __restrict__ C)          // [B][520][520]
{
    __shared__ float As[GT][GP];
    __shared__ float Ws[GT][GP];
    int t = threadIdx.x;
    int tx = t & 15, ty = t >> 4;
    int b = blockIdx.z;
    int m0 = blockIdx.y * GT, n0 = blockIdx.x * GT;
    int lr = t >> 2, lc = (t & 3) * 8;
    int mr = m0 + lr; if (mr >= NN) mr = NN - 1;
    int nr = n0 + lr; if (nr >= NN) nr = NN - 1;
    float acc[4][4];
    #pragma unroll
    for (int i = 0; i < 4; i++)
        #pragma unroll
        for (int j = 0; j < 4; j++) acc[i][j] = 0.0f;

    for (int k0 = 0; k0 < EE; k0 += GK) {
        const float* Ap = A + ((size_t)(b * NN + mr)) * EE + k0 + lc;
        const float* Wp = Enc + ((size_t)(b * NN + nr)) * EE + k0 + lc;
        float4 av0 = *((const float4*)Ap), av1 = *((const float4*)(Ap + 4));
        float4 wv0 = *((const float4*)Wp), wv1 = *((const float4*)(Wp + 4));
        *((float4*)&As[lr][lc]) = av0; *((float4*)&As[lr][lc + 4]) = av1;
        *((float4*)&Ws[lr][lc]) = wv0; *((float4*)&Ws[lr][lc + 4]) = wv1;
        __syncthreads();
        #pragma unroll
        for (int kk = 0; kk < GK; kk += 2) {
            float2 a0 = *((const float2*)&As[ty][kk]);
            float2 a1 = *((const float2*)&As[ty + 16][kk]);
            float2 a2 = *((const float2*)&As[ty + 32][kk]);
            float2 a3 = *((const float2*)&As[ty + 48][kk]);
            float2 w0 = *((const float2*)&Ws[tx][kk]);
            float2 w1 = *((const float2*)&Ws[tx + 16][kk]);
            float2 w2 = *((const float2*)&Ws[tx + 32][kk]);
            float2 w3 = *((const float2*)&Ws[tx + 48][kk]);
            acc[0][0] += a0.x * w0.x + a0.y * w0.y;
            acc[0][1] += a0.x * w1.x + a0.y * w1.y;
            acc[0][2] += a0.x * w2.x + a0.y * w2.y;
            acc[0][3] += a0.x * w3.x + a0.y * w3.y;
            acc[1][0] += a1.x * w0.x + a1.y * w0.y;
            acc[1][1] += a1.x * w1.x + a1.y * w1.y;
            acc[1][2] += a1.x * w2.x + a1.y * w2.y;
            acc[1][3] += a1.x * w3.x + a1.y * w3.y;
            acc[2][0] += a2.x * w0.x + a2.y * w0.y;
            acc[2][1] += a2.x * w1.x + a2.y * w1.y;
            acc[2][2] += a2.x * w2.x + a2.y * w2.y;
            acc[2][3] += a2.x * w3.x + a2.y * w3.y;
            acc[3][0] += a3.x * w0.x + a3.y * w0.y;
            acc[3][1] += a3.x * w1.x + a3.y * w1.y;
            acc[3][2] += a3.x * w2.x + a3.y * w2.y;
            acc[3][3] += a3.x * w3.x + a3.y * w3.y;
        }
        __syncthreads();
    }
    #pragma unroll
    for (int i = 0; i < 4; i++) {
        int m = m0 + ty + 16 * i;
        if (m >= NN) continue;
        #pragma unroll
        for (int j = 0; j < 4; j++) {
            int n = n0 + tx + 16 * j;
            if (n >= NN) continue;
            float v = 10.0f * tanhf(acc[i][j] * 0.088388347648318447f);
            C[((size_t)(b * NN + m)) * NN + n] = v;
        }
    }
}

// ---------------- row softmax: out = softmax(logits + mask) ----------------
__global__ __launch_bounds__(64) void smax_k(
    const float* __restrict__ L, const float* __restrict__ mask,
    float* __restrict__ out)
{
    int bm = blockIdx.x;
    int t = threadIdx.x;
    const float* Lr = L + (size_t)bm * NN;
    const float* Mr = mask + (size_t)bm * NN;
    float v[9];
    float mx = -1e30f;
    #pragma unroll
    for (int i = 0; i < 9; i++) {
        int idx = t + i * 64;
        if (idx < NN) { v[i] = Lr[idx] + Mr[idx]; mx = fmaxf(mx, v[i]); }
        else v[i] = -1e30f;
    }
    #pragma unroll
    for (int o = 32; o > 0; o >>= 1) mx = fmaxf(mx, __shfl_xor(mx, o));
    float s = 0.0f;
    #pragma unroll
    for (int i = 0; i < 9; i++) {
        int idx = t + i * 64;
        float e = (idx < NN) ? expf(v[i] - mx) : 0.0f;
        v[i] = e; s += e;
    }
    #pragma unroll
    for (int o = 32; o > 0; o >>= 1) s += __shfl_xor(s, o);
    float inv = 1.0f / s;
    #pragma unroll
    for (int i = 0; i < 9; i++) {
        int idx = t + i * 64;
        if (idx < NN) out[(size_t)bm * NN + idx] = v[i] * inv;
    }
}

// ---------------- register-tiled flash MHA (2 Q-rows/thread) ----------------
// 256 thr; tx=t&15 (4 k-cols each), ty=t>>4 (2 q-rows each -> TQ=32);
// dg=t&3 (V dim group), mg=(t>>2)&3 (PV m-subrange, stride 4 rows = conflict-free).
// NOTE: no min-waves in launch_bounds — forcing 5 waves/EU made the compiler
// spill qs[] to scratch (VGPR 48, FETCH 1.3GB, 573us). Natural alloc ~90 VGPR.
#define TQ 32
#define TK 64
__global__ __launch_bounds__(256) void fmha_k(
    const float* __restrict__ Q, const float* __restrict__ K,
    const float* __restrict__ V, const float* __restrict__ mask,
    float* __restrict__ O, int Nq, int Nk)
{
    int qt = blockIdx.x, h = blockIdx.y, b = blockIdx.z;
    int t = threadIdx.x;
    int tx = t & 15, ty = t >> 4;
    int dg = t & 3, mg = (t >> 2) & 3;
    int r_st = t >> 2, c_st = (t & 3) * 4;

    __shared__ float Kt[16][68];   // [dim][col]
    __shared__ float Vs[64][20];   // [m][dim]
    __shared__ float Ps[TQ][68];   // [row][m]

    int qr[2];
    float qs[2][16];
    #pragma unroll
    for (int i = 0; i < 2; i++) {
        int q = qt * TQ + ty * 2 + i;
        qr[i] = q;
        int qc = q < Nq ? q : Nq - 1;
        const float4* qp = (const float4*)(Q + ((size_t)(b * Nq + qc)) * EE + h * 16);
        #pragma unroll
        for (int c = 0; c < 4; c++) {
            float4 v = qp[c];
            qs[i][c * 4 + 0] = v.x; qs[i][c * 4 + 1] = v.y;
            qs[i][c * 4 + 2] = v.z; qs[i][c * 4 + 3] = v.w;
        }
    }

    float o[2][4];
    #pragma unroll
    for (int i = 0; i < 2; i++)
        #pragma unroll
        for (int j = 0; j < 4; j++) o[i][j] = 0.0f;
    float m_i[2] = {-1e30f, -1e30f};
    float l_i[2] = {0.0f, 0.0f};

    int nkt = (Nk + TK - 1) / TK;
    for (int kt = 0; kt < nkt; kt++) {
        int k0 = kt * TK;
        {
            int kr = k0 + r_st; int krc = kr < Nk ? kr : Nk - 1;
            float4 kv = *((const float4*)(K + ((size_t)(b * Nk + krc)) * EE + h * 16 + c_st));
            float4 vv = *((const float4*)(V + ((size_t)(b * Nk + krc)) * EE + h * 16 + c_st));
            Kt[c_st + 0][r_st] = kv.x;
            Kt[c_st + 1][r_st] = kv.y;
            Kt[c_st + 2][r_st] = kv.z;
            Kt[c_st + 3][r_st] = kv.w;
            *((float4*)&Vs[r_st][c_st]) = vv;
        }
        __syncthreads();

        // QK: s[2 rows][4 cols], cols = tx*4+j
        float s[2][4];
        #pragma unroll
        for (int i = 0; i < 2; i++)
            #pragma unroll
            for (int j = 0; j < 4; j++) s[i][j] = 0.0f;
        #pragma unroll
        for (int k = 0; k < 16; k++) {
            float4 kv4 = *((const float4*)&Kt[k][tx * 4]);
            #pragma unroll
            for (int i = 0; i < 2; i++) {
                float qv = qs[i][k];
                s[i][0] += qv * kv4.x;
                s[i][1] += qv * kv4.y;
                s[i][2] += qv * kv4.z;
                s[i][3] += qv * kv4.w;
            }
        }

        // scale + mask + col bounds
        int c0 = k0 + tx * 4;
        #pragma unroll
        for (int i = 0; i < 2; i++) {
            float mv0 = 0, mv1 = 0, mv2 = 0, mv3 = 0;
            if (mask) {
                int qc = qr[i] < Nq ? qr[i] : Nq - 1;
                const float* mr = mask + ((size_t)(b * Nq + qc)) * Nk;
                if (c0 + 3 < Nk) {
                    float4 m4 = *((const float4*)(mr + c0));
                    mv0 = m4.x; mv1 = m4.y; mv2 = m4.z; mv3 = m4.w;
                } else {
                    if (c0 + 0 < Nk) mv0 = mr[c0 + 0];
                    if (c0 + 1 < Nk) mv1 = mr[c0 + 1];
                    if (c0 + 2 < Nk) mv2 = mr[c0 + 2];
                    if (c0 + 3 < Nk) mv3 = mr[c0 + 3];
                }
            }
            s[i][0] = (c0 + 0 < Nk) ? (s[i][0] * 0.25f + mv0) : -1e30f;
            s[i][1] = (c0 + 1 < Nk) ? (s[i][1] * 0.25f + mv1) : -1e30f;
            s[i][2] = (c0 + 2 < Nk) ? (s[i][2] * 0.25f + mv2) : -1e30f;
            s[i][3] = (c0 + 3 < Nk) ? (s[i][3] * 0.25f + mv3) : -1e30f;
        }

        // online softmax per row (stats shared across tx lanes = bits 0-3)
        #pragma unroll
        for (int i = 0; i < 2; i++) {
            float mloc = fmaxf(fmaxf(s[i][0], s[i][1]), fmaxf(s[i][2], s[i][3]));
            mloc = fmaxf(mloc, __shfl_xor(mloc, 1));
            mloc = fmaxf(mloc, __shfl_xor(mloc, 2));
            mloc = fmaxf(mloc, __shfl_xor(mloc, 4));
            mloc = fmaxf(mloc, __shfl_xor(mloc, 8));
            float m_new = fmaxf(m_i[i], mloc);
            float alpha = __expf(m_i[i] - m_new);
            float p0 = __expf(s[i][0] - m_new);
            float p1 = __expf(s[i][1] - m_new);
            float p2 = __expf(s[i][2] - m_new);
            float p3 = __expf(s[i][3] - m_new);
            s[i][0] = p0; s[i][1] = p1; s[i][2] = p2; s[i][3] = p3;
            float ls = p0 + p1 + p2 + p3;
            ls += __shfl_xor(ls, 1);
            ls += __shfl_xor(ls, 2);
            ls += __shfl_xor(ls, 4);
            ls += __shfl_xor(ls, 8);
            l_i[i] = l_i[i] * alpha + ls;
            m_i[i] = m_new;
            o[i][0] *= alpha; o[i][1] *= alpha; o[i][2] *= alpha; o[i][3] *= alpha;
        }

        // write P (rows ty*2+i; per-phase 2-way = free)
        #pragma unroll
        for (int i = 0; i < 2; i++) {
            float4 pw; pw.x = s[i][0]; pw.y = s[i][1]; pw.z = s[i][2]; pw.w = s[i][3];
            *((float4*)&Ps[ty * 2 + i][tx * 4]) = pw;
        }
        __syncthreads();

        // PV: partial over m quads mq*16 + mg*4, dims dg*4..+3
        #pragma unroll
        for (int mq = 0; mq < 4; mq++) {
            int m0 = mq * 16 + mg * 4;
            float4 pr0 = *((const float4*)&Ps[ty * 2 + 0][m0]);
            float4 pr1 = *((const float4*)&Ps[ty * 2 + 1][m0]);
            float4 v0 = *((const float4*)&Vs[m0 + 0][dg * 4]);
            float4 v1 = *((const float4*)&Vs[m0 + 1][dg * 4]);
            float4 v2 = *((const float4*)&Vs[m0 + 2][dg * 4]);
            float4 v3 = *((const float4*)&Vs[m0 + 3][dg * 4]);
            o[0][0] += pr0.x * v0.x + pr0.y * v1.x + pr0.z * v2.x + pr0.w * v3.x;
            o[0][1] += pr0.x * v0.y + pr0.y * v1.y + pr0.z * v2.y + pr0.w * v3.y;
            o[0][2] += pr0.x * v0.z + pr0.y * v1.z + pr0.z * v2.z + pr0.w * v3.z;
            o[0][3] += pr0.x * v0.w + pr0.y * v1.w + pr0.z * v2.w + pr0.w * v3.w;
            o[1][0] += pr1.x * v0.x + pr1.y * v1.x + pr1.z * v2.x + pr1.w * v3.x;
            o[1][1] += pr1.x * v0.y + pr1.y * v1.y + pr1.z * v2.y + pr1.w * v3.y;
            o[1][2] += pr1.x * v0.z + pr1.y * v1.z + pr1.z * v2.z + pr1.w * v3.z;
            o[1][3] += pr1.x * v0.w + pr1.y * v1.w + pr1.z * v2.w + pr1.w * v3.w;
        }
        __syncthreads();
    }

    // reduce partial O over mg (lane bits 2,3)
    #pragma unroll
    for (int i = 0; i < 2; i++)
        #pragma unroll
        for (int j = 0; j < 4; j++) {
            o[i][j] += __shfl_xor(o[i][j], 4);
            o[i][j] += __shfl_xor(o[i][j], 8);
        }
    if (mg == 0) {
        #pragma unroll
        for (int i = 0; i < 2; i++) {
            if (qr[i] < Nq) {
                float inv = 1.0f / l_i[i];
                float4 ov;
                ov.x = o[i][0] * inv; ov.y = o[i][1] * inv;
                ov.z = o[i][2] * inv; ov.w = o[i][3] * inv;
                *((float4*)(O + ((size_t)(b * Nq + qr[i])) * EE + h * 16 + dg * 4)) = ov;
            }
        }
    }
}

// ---------------- InstanceNorm over node axis ----------------
__global__ __launch_bounds__(64) void inorm_k(
    const float* __restrict__ X, const float* __restrict__ Y,
    const float* __restrict__ g, const float* __restrict__ bb,
    float* __restrict__ Out)
{
    int be = blockIdx.x;
    int b = be >> 7, e = be & 127;
    int t = threadIdx.x;
    float vals[9];
    float s = 0.0f, s2 = 0.0f;
    int c = 0;
    for (int n = t; n < NN; n += 64) {
        size_t off = ((size_t)(b * NN + n)) * EE + e;
        float v = X[off] + Y[off];
        vals[c++] = v; s += v; s2 += v * v;
    }
    #pragma unroll
    for (int o = 32; o > 0; o >>= 1) { s += __shfl_down(s, o); s2 += __shfl_down(s2, o); }
    s = __shfl(s, 0); s2 = __shfl(s2, 0);
    float mu = s * (1.0f / NN);
    float var = s2 * (1.0f / NN) - mu * mu;
    float inv = rsqrtf(var + 1e-5f);
    float gg = g[e], bv = bb[e];
    c = 0;
    for (int n = t; n < NN; n += 64) {
        size_t off = ((size_t)(b * NN + n)) * EE + e;
        Out[off] = (vals[c++] - mu) * inv * gg + bv;
    }
}

__global__ void zero_k(float* p, int n) {
    int i = blockIdx.x * 256 + threadIdx.x;
    if (i < n) p[i] = 0.0f;
}

__global__ __launch_bounds__(128) void encsum_k(const float* __restrict__ enc, float* __restrict__ esum) {
    int b = blockIdx.x, ch = blockIdx.y, t = threadIdx.x;
    float a = 0.0f;
    for (int i = 0; i < 65; i++) {
        int n = ch * 65 + i;
        a += enc[((size_t)(b * NN + n)) * EE + t];
    }
    atomicAdd(&esum[b * EE + t], a);
}

// mt[b,e] = sum_f (esum[b,f]/N) * Wr[e, 128+f]
__global__ __launch_bounds__(128) void meanterm_k(
    const float* __restrict__ esum, const float* __restrict__ Wr, float* __restrict__ mt)
{
    int b = blockIdx.x, t = threadIdx.x;
    __shared__ float em[128];
    em[t] = esum[b * EE + t] * (1.0f / NN);
    __syncthreads();
    const float* w = Wr + (size_t)t * 257 + 128;
    float a = 0.0f;
    for (int f = 0; f < 128; f++) a += em[f] * w[f];
    mt[b * EE + t] = a;
}

__global__ __launch_bounds__(128) void subtour_k(
    const float* __restrict__ enc, const int* __restrict__ subn,
    const int* __restrict__ subl, float* __restrict__ subm)
{
    int bm = blockIdx.x;
    int b = bm / MM;
    int t = threadIdx.x;
    int len = subl[bm];
    float acc = 0.0f; int cnt = 0;
    for (int l = 0; l < LL; l++) {
        int node = subn[(size_t)bm * LL + l];
        if (l < len && node >= DEPOT_) {
            acc += enc[((size_t)(b * NN + node)) * EE + t];
            cnt++;
        }
    }
    float cf = (float)(cnt < 1 ? 1 : cnt);
    subm[(size_t)bm * EE + t] = acc / cf;
}

__global__ __launch_bounds__(128) void decq_k(
    const float* __restrict__ enc, const float* __restrict__ subm,
    const float* __restrict__ mterm, const int* __restrict__ cur,
    const float* __restrict__ loadv, const int* __restrict__ sel,
    const float* __restrict__ Wl, const float* __restrict__ Wr,
    float* __restrict__ out)
{
    int bm = blockIdx.x;
    int b = bm / MM;
    int t = threadIdx.x;
    __shared__ float le[128], sm[128];
    int cn = cur[bm];
    le[t] = enc[((size_t)(b * NN + cn)) * EE + t];
    sm[t] = subm[(size_t)bm * EE + t];
    __syncthreads();
    int s2v = sel[(size_t)bm * 4 + 2];   // selected[:,:,-2]
    bool flag = (s2v >= DEPOT_) && (cn < DEPOT_);
    float q;
    if (flag) {
        const float* w = Wl + (size_t)t * 256;
        float a = 0.0f;
        for (int f = 0; f < 128; f++) a += le[f] * w[f];
        for (int f = 0; f < 128; f++) a += sm[f] * w[128 + f];
        q = a;
    } else {
        const float* w = Wr + (size_t)t * 257;
        float a = mterm[b * EE + t] + loadv[bm] * w[256];
        for (int f = 0; f < 128; f++) a += le[f] * w[f];
        q = a;
    }
    out[(size_t)bm * EE + t] = q;
}

extern "C" void kernel_launch(void* const* d_in, const int* in_sizes, int n_in,
                              void* d_out, int out_size, void* d_ws, size_t ws_size,
                              hipStream_t stream)
{
    const float* depot = (const float*)d_in[0];
    const float* cust  = (const float*)d_in[1];
    const float* mask  = (const float*)d_in[2];
    const float* loadv = (const float*)d_in[3];
    const int*  cur   = (const int*)d_in[4];
    const int*  subn  = (const int*)d_in[5];
    const int*  subl  = (const int*)d_in[6];
    const int*  sel   = (const int*)d_in[7];
    const float* Wdep  = (const float*)d_in[8];
    const float* bdep  = (const float*)d_in[9];
    const float* Wcus  = (const float*)d_in[10];
    const float* bcus  = (const float*)d_in[11];
    const float* Wq    = (const float*)d_in[12];
    const float* Wk    = (const float*)d_in[13];
    const float* Wv    = (const float*)d_in[14];
    const float* Wc    = (const float*)d_in[15];
    const float* Wcb   = (const float*)d_in[16];
    const float* n1g   = (const float*)d_in[17];
    const float* n1b   = (const float*)d_in[18];
    const float* fW1   = (const float*)d_in[19];
    const float* fb1   = (const float*)d_in[20];
    const float* fW2   = (const float*)d_in[21];
    const float* fb2   = (const float*)d_in[22];
    const float* n2g   = (const float*)d_in[23];
    const float* n2b   = (const float*)d_in[24];
    const float* Wql   = (const float*)d_in[25];
    const float* Wqr   = (const float*)d_in[26];
    const float* dWk   = (const float*)d_in[27];
    const float* dWv   = (const float*)d_in[28];
    const float* dWc   = (const float*)d_in[29];
    const float* dWcb  = (const float*)d_in[30];

    const size_t SZ = (size_t)BB * NN * EE;           // 2,129,920
    float* f0 = (float*)d_ws;       // x / encoded
    float* f1 = f0 + SZ;            // q / k_d / logits (spans f1..f5)
    float* f2 = f1 + SZ;            // k / v_d
    float* f3 = f2 + SZ;            // v / encsum + meanterm
    float* f4 = f3 + SZ;            // mh,ff2 out / sub_mean, dec attn
    float* f5 = f4 + SZ;            // x1 / final_q
    float* big = f5 + SZ;           // ffh (B*N*FFH) / dec score

    dim3 g4(EE / GT, (BB * NN) / GT);     // (2, 260)
    dim3 g16(FFH_ / GT, (BB * NN) / GT);  // (8, 260)
    dim3 gmha((NN + TQ - 1) / TQ, HH, BB);  // (17, 8, 32)
    dim3 gsc((NN + GT - 1) / GT, (NN + GT - 1) / GT, BB);  // (9, 9, 32)

    embed_k<<<(BB * NN * EE) / 256, 256, 0, stream>>>(depot, cust, Wdep, bdep, Wcus, bcus, f0);

    for (int i = 0; i < NL_; i++) {
        const float* wq = Wq + (size_t)i * EE * EE;
        const float* wk = Wk + (size_t)i * EE * EE;
        const float* wv = Wv + (size_t)i * EE * EE;
        const float* wc = Wc + (size_t)i * EE * EE;
        gemm64_k<<<g4, 256, 0, stream>>>(f0, EE, wq, EE, nullptr, f1, EE, EE, 0);
        gemm64_k<<<g4, 256, 0, stream>>>(f0, EE, wk, EE, nullptr, f2, EE, EE, 0);
        gemm64_k<<<g4, 256, 0, stream>>>(f0, EE, wv, EE, nullptr, f3, EE, EE, 0);
        fmha_k<<<gmha, 256, 0, stream>>>(f1, f2, f3, nullptr, f4, NN, NN);
        gemm64_k<<<g4, 256, 0, stream>>>(f4, EE, wc, EE, Wcb + i * EE, f1, EE, EE, 0);
        inorm_k<<<BB * EE, 64, 0, stream>>>(f0, f1, n1g + i * EE, n1b + i * EE, f5);
        gemm64_k<<<g16, 256, 0, stream>>>(f5, EE, fW1 + (size_t)i * FFH_ * EE, EE, fb1 + i * FFH_, big, FFH_, EE, 1);
        gemm64_k<<<g4, 256, 0, stream>>>(big, FFH_, fW2 + (size_t)i * EE * FFH_, FFH_, fb2 + i * EE, f1, EE, FFH_, 0);
        inorm_k<<<BB * EE, 64, 0, stream>>>(f5, f1, n2g + i * EE, n2b + i * EE, f0);
    }

    // ---- decoder ----
    gemm64_k<<<g4, 256, 0, stream>>>(f0, EE, dWk, EE, nullptr, f1, EE, EE, 0);
    gemm64_k<<<g4, 256, 0, stream>>>(f0, EE, dWv, EE, nullptr, f2, EE, EE, 0);

    zero_k<<<(BB * EE + 255) / 256, 256, 0, stream>>>(f3, BB * EE);
    encsum_k<<<dim3(BB, 8), 128, 0, stream>>>(f0, f3);
    meanterm_k<<<BB, 128, 0, stream>>>(f3, Wqr, f3 + BB * EE);

    subtour_k<<<BB * MM, 128, 0, stream>>>(f0, subn, subl, f4);
    decq_k<<<BB * MM, 128, 0, stream>>>(f0, f4, f3 + BB * EE, cur, loadv, sel, Wql, Wqr, f5);

    fmha_k<<<gmha, 256, 0, stream>>>(f5, f1, f2, mask, f4, MM, NN);
    // dec score -> big (keeps f1..f5 free for the logits matrix)
    gemm64_k<<<g4, 256, 0, stream>>>(f4, EE, dWc, EE, dWcb, big, EE, EE, 0);

    // logits (B x 520 x 520) at f1 (spans f1..f5; all dead now)
    sgemm_k<<<gsc, 256, 0, stream>>>(big, f0, f1);
    smax_k<<<BB * MM, 64, 0, stream>>>(f1, mask, (float*)d_out);
}

// Round 9
// 2704.718 us; speedup vs baseline: 2.1578x; 1.2350x over previous
//
#include <hip/hip_runtime.h>
#include <hip/hip_bf16.h>

#define BB 32
#define NN 520
#define MM 520
#define EE 128
#define HH 8
#define DKK 16
#define FFH_ 512
#define NL_ 6
#define DEPOT_ 20
#define LL 40

typedef short short8 __attribute__((ext_vector_type(8)));
typedef float floatx4 __attribute__((ext_vector_type(4)));

__device__ __forceinline__ unsigned short f2b(float x) {
    unsigned int u = __float_as_uint(x);
    return (unsigned short)((u + 0x7fffu + ((u >> 16) & 1u)) >> 16);
}
__device__ __forceinline__ float b2f_(unsigned short h) {
    return __uint_as_float(((unsigned int)h) << 16);
}

// ---------------- embedding: depot/customer linear ----------------
__global__ __launch_bounds__(256) void embed_k(
    const float* __restrict__ dep, const float* __restrict__ cus,
    const float* __restrict__ Wd, const float* __restrict__ bd,
    const float* __restrict__ Wc3, const float* __restrict__ bc,
    float* __restrict__ x)
{
    int idx = blockIdx.x * 256 + threadIdx.x;   // < B*N*E = 2129920
    int e = idx & 127;
    int bn = idx >> 7;
    int n = bn % NN;
    int b = bn / NN;
    float a;
    if (n < DEPOT_) {
        a = bd[e];
        const float* f = dep + ((size_t)(b * DEPOT_ + n)) * 4;
        #pragma unroll
        for (int j = 0; j < 4; j++) a += f[j] * Wd[e * 4 + j];
    } else {
        a = bc[e];
        const float* f = cus + ((size_t)(b * 500 + (n - DEPOT_))) * 3;
        #pragma unroll
        for (int j = 0; j < 3; j++) a += f[j] * Wc3[e * 3 + j];
    }
    x[idx] = a;
}

// ---------------- bf16x3 MFMA GEMM: C[m,n] = sum_k A[m,k]*W[n,k] + bias[n] ----------------
// Block tile 128(m) x 64(n), BK=32, 4 waves. Each value split a = hi(bf16) + lo(bf16);
// A*B ~= AhBh + AhBl + AlBh (error ~2^-17 relative, fp32-equivalent here).
// Frag layouts (verified m89/m120): A/B idx=lane&15, k=(lane>>4)*8+j; C col=lane&15,
// row=(lane>>4)*4+reg. Rows padded to 40 shorts (80B) -> 16B-aligned, 2-way banks (free).
#define AP 40
__global__ __launch_bounds__(256) void gemm_mfma_k(
    const float* __restrict__ A, int lda,
    const float* __restrict__ W, int ldw,
    const float* __restrict__ bias,
    float* __restrict__ C, int ldc,
    int K, int relu)
{
    __shared__ __align__(16) unsigned short Ah[128][AP];
    __shared__ __align__(16) unsigned short Al[128][AP];
    __shared__ __align__(16) unsigned short Bh[64][AP];
    __shared__ __align__(16) unsigned short Bl[64][AP];

    int t = threadIdx.x;
    int w = t >> 6, lane = t & 63;
    int frow = lane & 15, fq = lane >> 4;
    int n0 = blockIdx.x * 64, m0 = blockIdx.y * 128;

    int arow = t & 127, ahalf = (t >> 7) * 16;   // A: 128 rows x 32 cols, 16 floats/thread
    int brow = t & 63,  bq    = (t >> 6) * 8;    // B: 64 rows x 32 cols, 8 floats/thread

    floatx4 acc[2][4];
    #pragma unroll
    for (int i = 0; i < 2; i++)
        #pragma unroll
        for (int j = 0; j < 4; j++)
            acc[i][j] = (floatx4){0.0f, 0.0f, 0.0f, 0.0f};

    for (int k0 = 0; k0 < K; k0 += 32) {
        // ---- stage A (hi/lo bf16) ----
        {
            const float* Ap = A + (size_t)(m0 + arow) * lda + k0 + ahalf;
            float vr[16];
            #pragma unroll
            for (int j = 0; j < 4; j++) {
                float4 v = ((const float4*)Ap)[j];
                vr[j * 4 + 0] = v.x; vr[j * 4 + 1] = v.y;
                vr[j * 4 + 2] = v.z; vr[j * 4 + 3] = v.w;
            }
            short8 hv0, hv1, lv0, lv1;
            #pragma unroll
            for (int j = 0; j < 8; j++) {
                unsigned short h = f2b(vr[j]);
                hv0[j] = (short)h;
                lv0[j] = (short)f2b(vr[j] - b2f_(h));
            }
            #pragma unroll
            for (int j = 0; j < 8; j++) {
                unsigned short h = f2b(vr[8 + j]);
                hv1[j] = (short)h;
                lv1[j] = (short)f2b(vr[8 + j] - b2f_(h));
            }
            *((short8*)&Ah[arow][ahalf])     = hv0;
            *((short8*)&Ah[arow][ahalf + 8]) = hv1;
            *((short8*)&Al[arow][ahalf])     = lv0;
            *((short8*)&Al[arow][ahalf + 8]) = lv1;
        }
        // ---- stage B (hi/lo bf16) ----
        {
            const float* Wp = W + (size_t)(n0 + brow) * ldw + k0 + bq;
            float4 v0 = ((const float4*)Wp)[0];
            float4 v1 = ((const float4*)Wp)[1];
            float wr[8] = {v0.x, v0.y, v0.z, v0.w, v1.x, v1.y, v1.z, v1.w};
            short8 hv, lv;
            #pragma unroll
            for (int j = 0; j < 8; j++) {
                unsigned short h = f2b(wr[j]);
                hv[j] = (short)h;
                lv[j] = (short)f2b(wr[j] - b2f_(h));
            }
            *((short8*)&Bh[brow][bq]) = hv;
            *((short8*)&Bl[brow][bq]) = lv;
        }
        __syncthreads();

        // ---- MFMA: 2 m-tiles x 4 n-tiles x 3 passes ----
        short8 ah0 = *((const short8*)&Ah[w * 32 + frow][fq * 8]);
        short8 ah1 = *((const short8*)&Ah[w * 32 + 16 + frow][fq * 8]);
        short8 al0 = *((const short8*)&Al[w * 32 + frow][fq * 8]);
        short8 al1 = *((const short8*)&Al[w * 32 + 16 + frow][fq * 8]);
        #pragma unroll
        for (int nt = 0; nt < 4; nt++) {
            short8 bh = *((const short8*)&Bh[nt * 16 + frow][fq * 8]);
            short8 bl = *((const short8*)&Bl[nt * 16 + frow][fq * 8]);
            acc[0][nt] = __builtin_amdgcn_mfma_f32_16x16x32_bf16(ah0, bh, acc[0][nt], 0, 0, 0);
            acc[1][nt] = __builtin_amdgcn_mfma_f32_16x16x32_bf16(ah1, bh, acc[1][nt], 0, 0, 0);
            acc[0][nt] = __builtin_amdgcn_mfma_f32_16x16x32_bf16(ah0, bl, acc[0][nt], 0, 0, 0);
            acc[1][nt] = __builtin_amdgcn_mfma_f32_16x16x32_bf16(ah1, bl, acc[1][nt], 0, 0, 0);
            acc[0][nt] = __builtin_amdgcn_mfma_f32_16x16x32_bf16(al0, bh, acc[0][nt], 0, 0, 0);
            acc[1][nt] = __builtin_amdgcn_mfma_f32_16x16x32_bf16(al1, bh, acc[1][nt], 0, 0, 0);
        }
        __syncthreads();
    }

    // ---- epilogue ----
    #pragma unroll
    for (int nt = 0; nt < 4; nt++) {
        int col = n0 + nt * 16 + frow;
        float bv = bias ? bias[col] : 0.0f;
        #pragma unroll
        for (int mt = 0; mt < 2; mt++) {
            int rbase = m0 + w * 32 + mt * 16 + fq * 4;
            #pragma unroll
            for (int r = 0; r < 4; r++) {
                float v = acc[mt][nt][r] + bv;
                if (relu) v = fmaxf(v, 0.0f);
                C[(size_t)(rbase + r) * ldc + col] = v;
            }
        }
    }
}

// ---------------- score GEMM (NT) with tanh epilogue (fp32) ----------------
#define GT 64
#define GK 32
#define GP 36
__global__ __launch_bounds__(256) void sgemm_k(
    const float* __restrict__ A,    // score [B*520][128]
    const float* __restrict__ Enc,  // [B*520][128]
    float* __restrict__ C)          // [B][520][520]
{
    __shared__ float As[GT][GP];
    __shared__ float Ws[GT][GP];
    int t = threadIdx.x;
    int tx = t & 15, ty = t >> 4;
    int b = blockIdx.z;
    int m0 = blockIdx.y * GT, n0 = blockIdx.x * GT;
    int lr = t >> 2, lc = (t & 3) * 8;
    int mr = m0 + lr; if (mr >= NN) mr = NN - 1;
    int nr = n0 + lr; if (nr >= NN) nr = NN - 1;
    float acc[4][4];
    #pragma unroll
    for (int i = 0; i < 4; i++)
        #pragma unroll
        for (int j = 0; j < 4; j++) acc[i][j] = 0.0f;

    for (int k0 = 0; k0 < EE; k0 += GK) {
        const float* Ap = A + ((size_t)(b * NN + mr)) * EE + k0 + lc;
        const float* Wp = Enc + ((size_t)(b * NN + nr)) * EE + k0 + lc;
        float4 av0 = *((const float4*)Ap), av1 = *((const float4*)(Ap + 4));
        float4 wv0 = *((const float4*)Wp), wv1 = *((const float4*)(Wp + 4));
        *((float4*)&As[lr][lc]) = av0; *((float4*)&As[lr][lc + 4]) = av1;
        *((float4*)&Ws[lr][lc]) = wv0; *((float4*)&Ws[lr][lc + 4]) = wv1;
        __syncthreads();
        #pragma unroll
        for (int kk = 0; kk < GK; kk += 2) {
            float2 a0 = *((const float2*)&As[ty][kk]);
            float2 a1 = *((const float2*)&As[ty + 16][kk]);
            float2 a2 = *((const float2*)&As[ty + 32][kk]);
            float2 a3 = *((const float2*)&As[ty + 48][kk]);
            float2 w0 = *((const float2*)&Ws[tx][kk]);
            float2 w1 = *((const float2*)&Ws[tx + 16][kk]);
            float2 w2 = *((const float2*)&Ws[tx + 32][kk]);
            float2 w3 = *((const float2*)&Ws[tx + 48][kk]);
            acc[0][0] += a0.x * w0.x + a0.y * w0.y;
            acc[0][1] += a0.x * w1.x + a0.y * w1.y;
            acc[0][2] += a0.x * w2.x + a0.y * w2.y;
            acc[0][3] += a0.x * w3.x + a0.y * w3.y;
            acc[1][0] += a1.x * w0.x + a1.y * w0.y;
            acc[1][1] += a1.x * w1.x + a1.y * w1.y;
            acc[1][2] += a1.x * w2.x + a1.y * w2.y;
            acc[1][3] += a1.x * w3.x + a1.y * w3.y;
            acc[2][0] += a2.x * w0.x + a2.y * w0.y;
            acc[2][1] += a2.x * w1.x + a2.y * w1.y;
            acc[2][2] += a2.x * w2.x + a2.y * w2.y;
            acc[2][3] += a2.x * w3.x + a2.y * w3.y;
            acc[3][0] += a3.x * w0.x + a3.y * w0.y;
            acc[3][1] += a3.x * w1.x + a3.y * w1.y;
            acc[3][2] += a3.x * w2.x + a3.y * w2.y;
            acc[3][3] += a3.x * w3.x + a3.y * w3.y;
        }
        __syncthreads();
    }
    #pragma unroll
    for (int i = 0; i < 4; i++) {
        int m = m0 + ty + 16 * i;
        if (m >= NN) continue;
        #pragma unroll
        for (int j = 0; j < 4; j++) {
            int n = n0 + tx + 16 * j;
            if (n >= NN) continue;
            float v = 10.0f * tanhf(acc[i][j] * 0.088388347648318447f);
            C[((size_t)(b * NN + m)) * NN + n] = v;
        }
    }
}

// ---------------- row softmax: out = softmax(logits + mask) ----------------
__global__ __launch_bounds__(64) void smax_k(
    const float* __restrict__ L, const float* __restrict__ mask,
    float* __restrict__ out)
{
    int bm = blockIdx.x;
    int t = threadIdx.x;
    const float* Lr = L + (size_t)bm * NN;
    const float* Mr = mask + (size_t)bm * NN;
    float v[9];
    float mx = -1e30f;
    #pragma unroll
    for (int i = 0; i < 9; i++) {
        int idx = t + i * 64;
        if (idx < NN) { v[i] = Lr[idx] + Mr[idx]; mx = fmaxf(mx, v[i]); }
        else v[i] = -1e30f;
    }
    #pragma unroll
    for (int o = 32; o > 0; o >>= 1) mx = fmaxf(mx, __shfl_xor(mx, o));
    float s = 0.0f;
    #pragma unroll
    for (int i = 0; i < 9; i++) {
        int idx = t + i * 64;
        float e = (idx < NN) ? expf(v[i] - mx) : 0.0f;
        v[i] = e; s += e;
    }
    #pragma unroll
    for (int o = 32; o > 0; o >>= 1) s += __shfl_xor(s, o);
    float inv = 1.0f / s;
    #pragma unroll
    for (int i = 0; i < 9; i++) {
        int idx = t + i * 64;
        if (idx < NN) out[(size_t)bm * NN + idx] = v[i] * inv;
    }
}

// ---------------- register-tiled flash MHA (2 Q-rows/thread) ----------------
// NOTE: no min-waves in launch_bounds — forcing 5 waves/EU made the compiler
// spill qs[] to scratch (VGPR 48, FETCH 1.3GB, 573us). Natural alloc 88 VGPR.
#define TQ 32
#define TK 64
__global__ __launch_bounds__(256) void fmha_k(
    const float* __restrict__ Q, const float* __restrict__ K,
    const float* __restrict__ V, const float* __restrict__ mask,
    float* __restrict__ O, int Nq, int Nk)
{
    int qt = blockIdx.x, h = blockIdx.y, b = blockIdx.z;
    int t = threadIdx.x;
    int tx = t & 15, ty = t >> 4;
    int dg = t & 3, mg = (t >> 2) & 3;
    int r_st = t >> 2, c_st = (t & 3) * 4;

    __shared__ float Kt[16][68];   // [dim][col]
    __shared__ float Vs[64][20];   // [m][dim]
    __shared__ float Ps[TQ][68];   // [row][m]

    int qr[2];
    float qs[2][16];
    #pragma unroll
    for (int i = 0; i < 2; i++) {
        int q = qt * TQ + ty * 2 + i;
        qr[i] = q;
        int qc = q < Nq ? q : Nq - 1;
        const float4* qp = (const float4*)(Q + ((size_t)(b * Nq + qc)) * EE + h * 16);
        #pragma unroll
        for (int c = 0; c < 4; c++) {
            float4 v = qp[c];
            qs[i][c * 4 + 0] = v.x; qs[i][c * 4 + 1] = v.y;
            qs[i][c * 4 + 2] = v.z; qs[i][c * 4 + 3] = v.w;
        }
    }

    float o[2][4];
    #pragma unroll
    for (int i = 0; i < 2; i++)
        #pragma unroll
        for (int j = 0; j < 4; j++) o[i][j] = 0.0f;
    float m_i[2] = {-1e30f, -1e30f};
    float l_i[2] = {0.0f, 0.0f};

    int nkt = (Nk + TK - 1) / TK;
    for (int kt = 0; kt < nkt; kt++) {
        int k0 = kt * TK;
        {
            int kr = k0 + r_st; int krc = kr < Nk ? kr : Nk - 1;
            float4 kv = *((const float4*)(K + ((size_t)(b * Nk + krc)) * EE + h * 16 + c_st));
            float4 vv = *((const float4*)(V + ((size_t)(b * Nk + krc)) * EE + h * 16 + c_st));
            Kt[c_st + 0][r_st] = kv.x;
            Kt[c_st + 1][r_st] = kv.y;
            Kt[c_st + 2][r_st] = kv.z;
            Kt[c_st + 3][r_st] = kv.w;
            *((float4*)&Vs[r_st][c_st]) = vv;
        }
        __syncthreads();

        float s[2][4];
        #pragma unroll
        for (int i = 0; i < 2; i++)
            #pragma unroll
            for (int j = 0; j < 4; j++) s[i][j] = 0.0f;
        #pragma unroll
        for (int k = 0; k < 16; k++) {
            float4 kv4 = *((const float4*)&Kt[k][tx * 4]);
            #pragma unroll
            for (int i = 0; i < 2; i++) {
                float qv = qs[i][k];
                s[i][0] += qv * kv4.x;
                s[i][1] += qv * kv4.y;
                s[i][2] += qv * kv4.z;
                s[i][3] += qv * kv4.w;
            }
        }

        int c0 = k0 + tx * 4;
        #pragma unroll
        for (int i = 0; i < 2; i++) {
            float mv0 = 0, mv1 = 0, mv2 = 0, mv3 = 0;
            if (mask) {
                int qc = qr[i] < Nq ? qr[i] : Nq - 1;
                const float* mr = mask + ((size_t)(b * Nq + qc)) * Nk;
                if (c0 + 3 < Nk) {
                    float4 m4 = *((const float4*)(mr + c0));
                    mv0 = m4.x; mv1 = m4.y; mv2 = m4.z; mv3 = m4.w;
                } else {
                    if (c0 + 0 < Nk) mv0 = mr[c0 + 0];
                    if (c0 + 1 < Nk) mv1 = mr[c0 + 1];
                    if (c0 + 2 < Nk) mv2 = mr[c0 + 2];
                    if (c0 + 3 < Nk) mv3 = mr[c0 + 3];
                }
            }
            s[i][0] = (c0 + 0 < Nk) ? (s[i][0] * 0.25f + mv0) : -1e30f;
            s[i][1] = (c0 + 1 < Nk) ? (s[i][1] * 0.25f + mv1) : -1e30f;
            s[i][2] = (c0 + 2 < Nk) ? (s[i][2] * 0.25f + mv2) : -1e30f;
            s[i][3] = (c0 + 3 < Nk) ? (s[i][3] * 0.25f + mv3) : -1e30f;
        }

        #pragma unroll
        for (int i = 0; i < 2; i++) {
            float mloc = fmaxf(fmaxf(s[i][0], s[i][1]), fmaxf(s[i][2], s[i][3]));
            mloc = fmaxf(mloc, __shfl_xor(mloc, 1));
            mloc = fmaxf(mloc, __shfl_xor(mloc, 2));
            mloc = fmaxf(mloc, __shfl_xor(mloc, 4));
            mloc = fmaxf(mloc, __shfl_xor(mloc, 8));
            float m_new = fmaxf(m_i[i], mloc);
            float alpha = __expf(m_i[i] - m_new);
            float p0 = __expf(s[i][0] - m_new);
            float p1 = __expf(s[i][1] - m_new);
            float p2 = __expf(s[i][2] - m_new);
            float p3 = __expf(s[i][3] - m_new);
            s[i][0] = p0; s[i][1] = p1; s[i][2] = p2; s[i][3] = p3;
            float ls = p0 + p1 + p2 + p3;
            ls += __shfl_xor(ls, 1);
            ls += __shfl_xor(ls, 2);
            ls += __shfl_xor(ls, 4);
            ls += __shfl_xor(ls, 8);
            l_i[i] = l_i[i] * alpha + ls;
            m_i[i] = m_new;
            o[i][0] *= alpha; o[i][1] *= alpha; o[i][2] *= alpha; o[i][3] *= alpha;
        }

        #pragma unroll
        for (int i = 0; i < 2; i++) {
            float4 pw; pw.x = s[i][0]; pw.y = s[i][1]; pw.z = s[i][2]; pw.w = s[i][3];
            *((float4*)&Ps[ty * 2 + i][tx * 4]) = pw;
        }
        __syncthreads();

        #pragma unroll
        for (int mq = 0; mq < 4; mq++) {
            int m0 = mq * 16 + mg * 4;
            float4 pr0 = *((const float4*)&Ps[ty * 2 + 0][m0]);
            float4 pr1 = *((const float4*)&Ps[ty * 2 + 1][m0]);
            float4 v0 = *((const float4*)&Vs[m0 + 0][dg * 4]);
            float4 v1 = *((const float4*)&Vs[m0 + 1][dg * 4]);
            float4 v2 = *((const float4*)&Vs[m0 + 2][dg * 4]);
            float4 v3 = *((const float4*)&Vs[m0 + 3][dg * 4]);
            o[0][0] += pr0.x * v0.x + pr0.y * v1.x + pr0.z * v2.x + pr0.w * v3.x;
            o[0][1] += pr0.x * v0.y + pr0.y * v1.y + pr0.z * v2.y + pr0.w * v3.y;
            o[0][2] += pr0.x * v0.z + pr0.y * v1.z + pr0.z * v2.z + pr0.w * v3.z;
            o[0][3] += pr0.x * v0.w + pr0.y * v1.w + pr0.z * v2.w + pr0.w * v3.w;
            o[1][0] += pr1.x * v0.x + pr1.y * v1.x + pr1.z * v2.x + pr1.w * v3.x;
            o[1][1] += pr1.x * v0.y + pr1.y * v1.y + pr1.z * v2.y + pr1.w * v3.y;
            o[1][2] += pr1.x * v0.z + pr1.y * v1.z + pr1.z * v2.z + pr1.w * v3.z;
            o[1][3] += pr1.x * v0.w + pr1.y * v1.w + pr1.z * v2.w + pr1.w * v3.w;
        }
        __syncthreads();
    }

    #pragma unroll
    for (int i = 0; i < 2; i++)
        #pragma unroll
        for (int j = 0; j < 4; j++) {
            o[i][j] += __shfl_xor(o[i][j], 4);
            o[i][j] += __shfl_xor(o[i][j], 8);
        }
    if (mg == 0) {
        #pragma unroll
        for (int i = 0; i < 2; i++) {
            if (qr[i] < Nq) {
                float inv = 1.0f / l_i[i];
                float4 ov;
                ov.x = o[i][0] * inv; ov.y = o[i][1] * inv;
                ov.z = o[i][2] * inv; ov.w = o[i][3] * inv;
                *((float4*)(O + ((size_t)(b * Nq + qr[i])) * EE + h * 16 + dg * 4)) = ov;
            }
        }
    }
}

// ---------------- InstanceNorm over node axis ----------------
__global__ __launch_bounds__(64) void inorm_k(
    const float* __restrict__ X, const float* __restrict__ Y,
    const float* __restrict__ g, const float* __restrict__ bb,
    float* __restrict__ Out)
{
    int be = blockIdx.x;
    int b = be >> 7, e = be & 127;
    int t = threadIdx.x;
    float vals[9];
    float s = 0.0f, s2 = 0.0f;
    int c = 0;
    for (int n = t; n < NN; n += 64) {
        size_t off = ((size_t)(b * NN + n)) * EE + e;
        float v = X[off] + Y[off];
        vals[c++] = v; s += v; s2 += v * v;
    }
    #pragma unroll
    for (int o = 32; o > 0; o >>= 1) { s += __shfl_down(s, o); s2 += __shfl_down(s2, o); }
    s = __shfl(s, 0); s2 = __shfl(s2, 0);
    float mu = s * (1.0f / NN);
    float var = s2 * (1.0f / NN) - mu * mu;
    float inv = rsqrtf(var + 1e-5f);
    float gg = g[e], bv = bb[e];
    c = 0;
    for (int n = t; n < NN; n += 64) {
        size_t off = ((size_t)(b * NN + n)) * EE + e;
        Out[off] = (vals[c++] - mu) * inv * gg + bv;
    }
}

__global__ void zero_k(float* p, int n) {
    int i = blockIdx.x * 256 + threadIdx.x;
    if (i < n) p[i] = 0.0f;
}

__global__ __launch_bounds__(128) void encsum_k(const float* __restrict__ enc, float* __restrict__ esum) {
    int b = blockIdx.x, ch = blockIdx.y, t = threadIdx.x;
    float a = 0.0f;
    for (int i = 0; i < 65; i++) {
        int n = ch * 65 + i;
        a += enc[((size_t)(b * NN + n)) * EE + t];
    }
    atomicAdd(&esum[b * EE + t], a);
}

// mt[b,e] = sum_f (esum[b,f]/N) * Wr[e, 128+f]
__global__ __launch_bounds__(128) void meanterm_k(
    const float* __restrict__ esum, const float* __restrict__ Wr, float* __restrict__ mt)
{
    int b = blockIdx.x, t = threadIdx.x;
    __shared__ float em[128];
    em[t] = esum[b * EE + t] * (1.0f / NN);
    __syncthreads();
    const float* w = Wr + (size_t)t * 257 + 128;
    float a = 0.0f;
    for (int f = 0; f < 128; f++) a += em[f] * w[f];
    mt[b * EE + t] = a;
}

__global__ __launch_bounds__(128) void subtour_k(
    const float* __restrict__ enc, const int* __restrict__ subn,
    const int* __restrict__ subl, float* __restrict__ subm)
{
    int bm = blockIdx.x;
    int b = bm / MM;
    int t = threadIdx.x;
    int len = subl[bm];
    float acc = 0.0f; int cnt = 0;
    for (int l = 0; l < LL; l++) {
        int node = subn[(size_t)bm * LL + l];
        if (l < len && node >= DEPOT_) {
            acc += enc[((size_t)(b * NN + node)) * EE + t];
            cnt++;
        }
    }
    float cf = (float)(cnt < 1 ? 1 : cnt);
    subm[(size_t)bm * EE + t] = acc / cf;
}

__global__ __launch_bounds__(128) void decq_k(
    const float* __restrict__ enc, const float* __restrict__ subm,
    const float* __restrict__ mterm, const int* __restrict__ cur,
    const float* __restrict__ loadv, const int* __restrict__ sel,
    const float* __restrict__ Wl, const float* __restrict__ Wr,
    float* __restrict__ out)
{
    int bm = blockIdx.x;
    int b = bm / MM;
    int t = threadIdx.x;
    __shared__ float le[128], sm[128];
    int cn = cur[bm];
    le[t] = enc[((size_t)(b * NN + cn)) * EE + t];
    sm[t] = subm[(size_t)bm * EE + t];
    __syncthreads();
    int s2v = sel[(size_t)bm * 4 + 2];   // selected[:,:,-2]
    bool flag = (s2v >= DEPOT_) && (cn < DEPOT_);
    float q;
    if (flag) {
        const float* w = Wl + (size_t)t * 256;
        float a = 0.0f;
        for (int f = 0; f < 128; f++) a += le[f] * w[f];
        for (int f = 0; f < 128; f++) a += sm[f] * w[128 + f];
        q = a;
    } else {
        const float* w = Wr + (size_t)t * 257;
        float a = mterm[b * EE + t] + loadv[bm] * w[256];
        for (int f = 0; f < 128; f++) a += le[f] * w[f];
        q = a;
    }
    out[(size_t)bm * EE + t] = q;
}

extern "C" void kernel_launch(void* const* d_in, const int* in_sizes, int n_in,
                              void* d_out, int out_size, void* d_ws, size_t ws_size,
                              hipStream_t stream)
{
    const float* depot = (const float*)d_in[0];
    const float* cust  = (const float*)d_in[1];
    const float* mask  = (const float*)d_in[2];
    const float* loadv = (const float*)d_in[3];
    const int*  cur   = (const int*)d_in[4];
    const int*  subn  = (const int*)d_in[5];
    const int*  subl  = (const int*)d_in[6];
    const int*  sel   = (const int*)d_in[7];
    const float* Wdep  = (const float*)d_in[8];
    const float* bdep  = (const float*)d_in[9];
    const float* Wcus  = (const float*)d_in[10];
    const float* bcus  = (const float*)d_in[11];
    const float* Wq    = (const float*)d_in[12];
    const float* Wk    = (const float*)d_in[13];
    const float* Wv    = (const float*)d_in[14];
    const float* Wc    = (const float*)d_in[15];
    const float* Wcb   = (const float*)d_in[16];
    const float* n1g   = (const float*)d_in[17];
    const float* n1b   = (const float*)d_in[18];
    const float* fW1   = (const float*)d_in[19];
    const float* fb1   = (const float*)d_in[20];
    const float* fW2   = (const float*)d_in[21];
    const float* fb2   = (const float*)d_in[22];
    const float* n2g   = (const float*)d_in[23];
    const float* n2b   = (const float*)d_in[24];
    const float* Wql   = (const float*)d_in[25];
    const float* Wqr   = (const float*)d_in[26];
    const float* dWk   = (const float*)d_in[27];
    const float* dWv   = (const float*)d_in[28];
    const float* dWc   = (const float*)d_in[29];
    const float* dWcb  = (const float*)d_in[30];

    const size_t SZ = (size_t)BB * NN * EE;           // 2,129,920
    float* f0 = (float*)d_ws;       // x / encoded
    float* f1 = f0 + SZ;            // q / k_d / logits (spans f1..f5)
    float* f2 = f1 + SZ;            // k / v_d
    float* f3 = f2 + SZ;            // v / encsum + meanterm
    float* f4 = f3 + SZ;            // mh,ff2 out / sub_mean, dec attn
    float* f5 = f4 + SZ;            // x1 / final_q
    float* big = f5 + SZ;           // ffh (B*N*FFH) / dec score

    dim3 g4(EE / 64, (BB * NN) / 128);     // (2, 130)
    dim3 g16(FFH_ / 64, (BB * NN) / 128);  // (8, 130)
    dim3 gmha((NN + TQ - 1) / TQ, HH, BB);  // (17, 8, 32)
    dim3 gsc((NN + GT - 1) / GT, (NN + GT - 1) / GT, BB);  // (9, 9, 32)

    embed_k<<<(BB * NN * EE) / 256, 256, 0, stream>>>(depot, cust, Wdep, bdep, Wcus, bcus, f0);

    for (int i = 0; i < NL_; i++) {
        const float* wq = Wq + (size_t)i * EE * EE;
        const float* wk = Wk + (size_t)i * EE * EE;
        const float* wv = Wv + (size_t)i * EE * EE;
        const float* wc = Wc + (size_t)i * EE * EE;
        gemm_mfma_k<<<g4, 256, 0, stream>>>(f0, EE, wq, EE, nullptr, f1, EE, EE, 0);
        gemm_mfma_k<<<g4, 256, 0, stream>>>(f0, EE, wk, EE, nullptr, f2, EE, EE, 0);
        gemm_mfma_k<<<g4, 256, 0, stream>>>(f0, EE, wv, EE, nullptr, f3, EE, EE, 0);
        fmha_k<<<gmha, 256, 0, stream>>>(f1, f2, f3, nullptr, f4, NN, NN);
        gemm_mfma_k<<<g4, 256, 0, stream>>>(f4, EE, wc, EE, Wcb + i * EE, f1, EE, EE, 0);
        inorm_k<<<BB * EE, 64, 0, stream>>>(f0, f1, n1g + i * EE, n1b + i * EE, f5);
        gemm_mfma_k<<<g16, 256, 0, stream>>>(f5, EE, fW1 + (size_t)i * FFH_ * EE, EE, fb1 + i * FFH_, big, FFH_, EE, 1);
        gemm_mfma_k<<<g4, 256, 0, stream>>>(big, FFH_, fW2 + (size_t)i * EE * FFH_, FFH_, fb2 + i * EE, f1, EE, FFH_, 0);
        inorm_k<<<BB * EE, 64, 0, stream>>>(f5, f1, n2g + i * EE, n2b + i * EE, f0);
    }

    // ---- decoder ----
    gemm_mfma_k<<<g4, 256, 0, stream>>>(f0, EE, dWk, EE, nullptr, f1, EE, EE, 0);
    gemm_mfma_k<<<g4, 256, 0, stream>>>(f0, EE, dWv, EE, nullptr, f2, EE, EE, 0);

    zero_k<<<(BB * EE + 255) / 256, 256, 0, stream>>>(f3, BB * EE);
    encsum_k<<<dim3(BB, 8), 128, 0, stream>>>(f0, f3);
    meanterm_k<<<BB, 128, 0, stream>>>(f3, Wqr, f3 + BB * EE);

    subtour_k<<<BB * MM, 128, 0, stream>>>(f0, subn, subl, f4);
    decq_k<<<BB * MM, 128, 0, stream>>>(f0, f4, f3 + BB * EE, cur, loadv, sel, Wql, Wqr, f5);

    fmha_k<<<gmha, 256, 0, stream>>>(f5, f1, f2, mask, f4, MM, NN);
    // dec score -> big (keeps f1..f5 free for the logits matrix)
    gemm_mfma_k<<<g4, 256, 0, stream>>>(f4, EE, dWc, EE, dWcb, big, EE, EE, 0);

    // logits (B x 520 x 520) at f1 (spans f1..f5; all dead now)
    sgemm_k<<<gsc, 256, 0, stream>>>(big, f0, f1);
    smax_k<<<BB * MM, 64, 0, stream>>>(f1, mask, (float*)d_out);
}